// Round 8
// baseline (269.467 us; speedup 1.0000x reference)
//
#include <hip/hip_runtime.h>
#include <hip/hip_cooperative_groups.h>
#include <math.h>

namespace cg = cooperative_groups;

#define BSZ 512
#define DD 2048
#define KK 128
#define PP 5
#define NCOL (KK * PP)   // 640
#define OUTW (DD + KK)   // 2176
#define LOG2E 1.4426950408889634f

#define KSPLIT 16
#define GK (DD / KSPLIT) // 128 k-depth per split
#define QSPLIT 8         // pairwise b2 chunks

typedef __attribute__((ext_vector_type(8))) short bf16x8;
typedef __attribute__((ext_vector_type(4))) float f32x4;

// ws layout (floats):
#define WS_NORM 0
#define WS_ACTV (WS_NORM + NCOL)                      // 640
#define WS_FPART (WS_ACTV + BSZ * NCOL)               // 328320
#define WS_XB (WS_FPART + QSPLIT * KK * BSZ)          // 852608 (512*2048 ushort)
#define WS_THT (WS_XB + BSZ * DD / 2)                 // 1376896 (640*2048 ushort)
#define WS_PART (WS_THT + NCOL * DD / 2)              // 2032256 (16*512*640 ushort)

__device__ inline ushort f2b(float f) {               // f32 -> bf16 RNE
    unsigned u = __float_as_uint(f);
    u += 0x7FFF + ((u >> 16) & 1);
    return (ushort)(u >> 16);
}
__device__ inline float b2f(ushort h) {
    return __uint_as_float((unsigned)h << 16);
}

// XOR-swizzled LDS index (ushort units).
#define SWZ(r, c) ((((r) * 128) + ((c) ^ (((r) & 7) << 3))))

// ---------------------------------------------------------------------------
// Kernel 1 (prep): [0,80) norm = colsum theta^2; [80,400) theta -> bf16
// transposed [640 n][2048 k]; [400,656) x -> bf16 [512][2048].
// ---------------------------------------------------------------------------
__global__ __launch_bounds__(256) void prep_kernel(const float* __restrict__ theta,
                                                   const float* __restrict__ x,
                                                   float* __restrict__ norm,
                                                   ushort* __restrict__ thT,
                                                   ushort* __restrict__ xb) {
    __shared__ float partial[32][8];
    __shared__ ushort sT[64][68];   // [n][k] tile; stride 68: write 8-way, read 2-way

    const int bid = blockIdx.x;
    const int t   = threadIdx.x;

    if (bid < 80) {                 // ---- norm ----
        const int c8  = bid * 8;
        const int col = c8 + (t & 7);
        const int g   = t >> 3;
        const float* p = theta + (size_t)g * NCOL + col;
        float s = 0.f;
#pragma unroll
        for (int j = 0; j < 64; ++j) {
            float v = p[(size_t)j * 32 * NCOL];
            s += v * v;
        }
        partial[g][t & 7] = s;
        __syncthreads();
        if (t < 8) {
            float acc = 0.f;
#pragma unroll
            for (int gg = 0; gg < 32; ++gg) acc += partial[gg][t];
            norm[c8 + t] = acc;
        }
    } else if (bid < 400) {         // ---- theta transpose+convert, 64x64 tiles ----
        const int tb    = bid - 80;        // 0..319 = 32 ktiles x 10 ntiles
        const int kz    = (tb & 31) * 64;
        const int nz    = (tb >> 5) * 64;
        const int c4    = t & 15;          // n-quad
        const int rbase = t >> 4;          // k-row base
#pragma unroll
        for (int i = 0; i < 4; ++i) {
            int r = rbase + i * 16;
            float4 v = *(const float4*)&theta[(size_t)(kz + r) * NCOL + nz + c4 * 4];
            sT[c4 * 4 + 0][r] = f2b(v.x);
            sT[c4 * 4 + 1][r] = f2b(v.y);
            sT[c4 * 4 + 2][r] = f2b(v.z);
            sT[c4 * 4 + 3][r] = f2b(v.w);
        }
        __syncthreads();
#pragma unroll
        for (int i = 0; i < 2; ++i) {
            int slot = t + i * 256;
            int rr   = slot >> 3;          // n row 0..63
            int cc   = (slot & 7) * 8;     // k col
            ushort4 w0 = *(const ushort4*)&sT[rr][cc];
            ushort4 w1 = *(const ushort4*)&sT[rr][cc + 4];
            ushort* dst = &thT[(size_t)(nz + rr) * DD + kz + cc];
            *(ushort4*)&dst[0] = w0;
            *(ushort4*)&dst[4] = w1;
        }
    } else {                        // ---- x convert ----
        const int b2 = bid - 400;          // 0..255
#pragma unroll
        for (int i = 0; i < 4; ++i) {
            int base = b2 * 4096 + i * 1024 + t * 4;
            float4 v = *(const float4*)&x[base];
            ushort4 w;
            w.x = f2b(v.x); w.y = f2b(v.y); w.z = f2b(v.z); w.w = f2b(v.w);
            *(ushort4*)&xb[base] = w;
        }
    }
}

// ---------------------------------------------------------------------------
// Kernel 2: split-K MFMA GEMM, ONE chunk per block (1280 blocks = 5/CU all
// resident; r7-verified). XCD swizzle: m-tile = bid&7 so each XCD's blocks
// share one xb m-stripe (256KB) + thT (2.5MB) = 2.75MB < 4MB L2 (was 4.5MB
// thrash). part stored bf16 (halves 42MB L3 round trip).
// Blocks [1280,1360): x -> out[:, :D] copy.
// ---------------------------------------------------------------------------
__global__ __launch_bounds__(256) void gemm_kernel(const ushort* __restrict__ xb,
                                                   const ushort* __restrict__ thT,
                                                   ushort* __restrict__ parth,
                                                   const float* __restrict__ x,
                                                   float* __restrict__ out) {
    __shared__ ushort lA[64 * 128];   // 16 KiB, swizzled
    __shared__ ushort lB[64 * 128];

    const int bx = blockIdx.x;
    if (bx >= 1280) {
        const int bid = bx - 1280;      // 0..79
        for (int i = bid * 256 + threadIdx.x; i < BSZ * (DD / 4); i += 80 * 256) {
            int r = i >> 9;
            int c = i & 511;
            float4 v = *(const float4*)&x[(size_t)r * DD + c * 4];
            *(float4*)&out[(size_t)r * OUTW + c * 4] = v;
        }
        return;
    }

    const int t    = threadIdx.x;
    const int lane = t & 63;
    const int wave = t >> 6;
    const int mt8  = bx & 7;           // m-tile -> XCD affinity (bid%8 round-robin)
    const int rest = bx >> 3;          // 0..159
    const int bn   = (rest % 10) * 64;
    const int bm   = mt8 * 64;
    const int z    = rest / 10;        // 0..15
    const int kz   = z * GK;

    const ushort* gA = xb  + (size_t)bm * DD + kz;
    const ushort* gB = thT + (size_t)bn * DD + kz;

    const int srr = t >> 4;          // staging row base
    const int sss = t & 15;          // staging slot

    uint4 va[4], vb[4];
#pragma unroll
    for (int i = 0; i < 4; ++i) {
        int rr = srr + i * 16;
        va[i] = *(const uint4*)&gA[(size_t)rr * DD + sss * 8];
        vb[i] = *(const uint4*)&gB[(size_t)rr * DD + sss * 8];
    }
#pragma unroll
    for (int i = 0; i < 4; ++i) {
        int rr = srr + i * 16;
        *(uint4*)&lA[SWZ(rr, sss * 8)] = va[i];
        *(uint4*)&lB[SWZ(rr, sss * 8)] = vb[i];
    }
    __syncthreads();

    const int fr = lane & 15;
    const int g  = lane >> 4;
    const int mr = (wave >> 1) * 32 + fr;
    const int nr = (wave & 1) * 32 + fr;

    f32x4 acc[2][2] = {};
#pragma unroll
    for (int ks = 0; ks < 4; ++ks) {
        const int kc = ks * 32 + g * 8;
        bf16x8 a0 = *(const bf16x8*)&lA[SWZ(mr,      kc)];
        bf16x8 a1 = *(const bf16x8*)&lA[SWZ(mr + 16, kc)];
        bf16x8 b0 = *(const bf16x8*)&lB[SWZ(nr,      kc)];
        bf16x8 b1 = *(const bf16x8*)&lB[SWZ(nr + 16, kc)];
        acc[0][0] = __builtin_amdgcn_mfma_f32_16x16x32_bf16(a0, b0, acc[0][0], 0, 0, 0);
        acc[0][1] = __builtin_amdgcn_mfma_f32_16x16x32_bf16(a0, b1, acc[0][1], 0, 0, 0);
        acc[1][0] = __builtin_amdgcn_mfma_f32_16x16x32_bf16(a1, b0, acc[1][0], 0, 0, 0);
        acc[1][1] = __builtin_amdgcn_mfma_f32_16x16x32_bf16(a1, b1, acc[1][1], 0, 0, 0);
    }

    // C/D map: col=lane&15, row=(lane>>4)*4+reg [m89-verified]
    ushort* base = parth + (size_t)z * (BSZ * NCOL);
#pragma unroll
    for (int mt = 0; mt < 2; ++mt)
#pragma unroll
        for (int nt = 0; nt < 2; ++nt) {
            int row = bm + (wave >> 1) * 32 + mt * 16 + g * 4;
            int col = bn + (wave & 1) * 32 + nt * 16 + fr;
            ushort* dst = base + (size_t)row * NCOL + col;
#pragma unroll
            for (int reg = 0; reg < 4; ++reg)
                dst[(size_t)reg * NCOL] = f2b(acc[mt][nt][reg]);
        }
}

// ---------------------------------------------------------------------------
// Kernel 3 (cooperative, 1024 blocks x 256 = 4 blocks/CU co-resident):
//   phase 1: reduce 16 bf16 split-K partials, fold scale -> actv
//   grid.sync()
//   phase 2: pairwise L1 -> exp2 -> f_part  (block = (k = bid&127, q = bid>>7))
//   grid.sync()
//   phase 3: freduce -> out[:, D:]
// Replaces 3 kernels (2 launch gaps ~8us) with 2 grid syncs.
// NO device-scope atomics anywhere (write-through to HBM, +30us measured r2).
// ---------------------------------------------------------------------------
__global__ __launch_bounds__(256, 4) void fused_kernel(const ushort* __restrict__ parth,
                                                       const float* __restrict__ norm,
                                                       const float* __restrict__ lws,
                                                       float* __restrict__ actv,
                                                       float* __restrict__ f_part,
                                                       const float* __restrict__ bias,
                                                       float* __restrict__ out) {
    cg::grid_group grid = cg::this_grid();
    const int tid = threadIdx.x;
    const int bid = blockIdx.x;

    __shared__ float sB[64][8];    // pairwise staging (2 KiB)

    // ---- phase 1: split-K reduce + scale ----
    {
        int i = bid * 256 + tid;
#pragma unroll
        for (int rep = 0; rep < 2; ++rep) {
            if (i < BSZ * NCOL) {
                int col = i % NCOL;
                float s = 0.f;
#pragma unroll
                for (int q = 0; q < KSPLIT; ++q)
                    s += b2f(parth[(size_t)q * (BSZ * NCOL) + i]);
                const float scale = __builtin_amdgcn_exp2f(lws[col] * LOG2E) *
                                    __builtin_amdgcn_rsqf(norm[col]) * LOG2E;
                actv[i] = s * scale;
            }
            i += 1024 * 256;
        }
    }
    grid.sync();

    // ---- phase 2: pairwise ----
    {
        const int k = bid & 127;
        const int q = bid >> 7;

        for (int i = tid; i < 64 * PP; i += 256) {
            int r = i / PP;
            int p = i - r * PP;
            sB[r][p] = actv[(size_t)(q * 64 + r) * NCOL + k * PP + p];
        }

        float a[2][PP];
#pragma unroll
        for (int r = 0; r < 2; ++r) {
            const float* ap = &actv[(size_t)(tid + r * 256) * NCOL + k * PP];
#pragma unroll
            for (int p = 0; p < PP; ++p) a[r][p] = ap[p];
        }
        __syncthreads();

        float acc[2] = {0.f, 0.f};
#pragma unroll 4
        for (int j = 0; j < 64; ++j) {
            const float4 v  = *(const float4*)&sB[j][0];
            const float  v4 = sB[j][4];
#pragma unroll
            for (int r = 0; r < 2; ++r) {
                float s = fabsf(a[r][0] - v.x) + fabsf(a[r][1] - v.y) +
                          fabsf(a[r][2] - v.z) + fabsf(a[r][3] - v.w) +
                          fabsf(a[r][4] - v4);
                acc[r] += __builtin_amdgcn_exp2f(-s);   // actv pre-scaled by log2e
            }
        }

        float* fp = f_part + ((size_t)q * KK + k) * BSZ;
        fp[tid]       = acc[0];
        fp[tid + 256] = acc[1];
    }
    grid.sync();

    // ---- phase 3: freduce ----
    {
        int i = bid * 256 + tid;
        if (i < BSZ * KK) {
            int k = i >> 9;
            int b = i & 511;
            float s = 0.f;
#pragma unroll
            for (int q = 0; q < QSPLIT; ++q)
                s += f_part[((size_t)q * KK + k) * BSZ + b];
            out[(size_t)b * OUTW + DD + k] = s - 1.0f + bias[k];
        }
    }
}

// ---------------------------------------------------------------------------
extern "C" void kernel_launch(void* const* d_in, const int* in_sizes, int n_in,
                              void* d_out, int out_size, void* d_ws, size_t ws_size,
                              hipStream_t stream) {
    const float* x     = (const float*)d_in[0];   // [512, 2048]
    const float* theta = (const float*)d_in[1];   // [2048, 128, 5]
    const float* lws   = (const float*)d_in[2];   // [128, 5]
    const float* bias  = (const float*)d_in[3];   // [128]
    float* out = (float*)d_out;                   // [512, 2176]

    float* ws     = (float*)d_ws;
    float* norm   = ws + WS_NORM;
    float* actv   = ws + WS_ACTV;
    float* f_part = ws + WS_FPART;
    ushort* xb    = (ushort*)(ws + WS_XB);
    ushort* thT   = (ushort*)(ws + WS_THT);
    ushort* parth = (ushort*)(ws + WS_PART);

    prep_kernel<<<656, 256, 0, stream>>>(theta, x, norm, thT, xb);
    gemm_kernel<<<1360, 256, 0, stream>>>(xb, thT, parth, x, out);

    const ushort* parth_c = parth;
    void* args[] = { (void*)&parth_c, (void*)&norm, (void*)&lws, (void*)&actv,
                     (void*)&f_part, (void*)&bias, (void*)&out };
    hipLaunchCooperativeKernel((void*)fused_kernel, dim3(1024), dim3(256),
                               args, 0, stream);
}

// Round 9
// 101.457 us; speedup vs baseline: 2.6560x; 2.6560x over previous
//
#include <hip/hip_runtime.h>
#include <math.h>

#define BSZ 512
#define DD 2048
#define KK 128
#define PP 5
#define NCOL (KK * PP)   // 640
#define OUTW (DD + KK)   // 2176
#define LOG2E 1.4426950408889634f

#define KSPLIT 16
#define GK (DD / KSPLIT) // 128 k-depth per split
#define QSPLIT 8         // pairwise b2 chunks

typedef __attribute__((ext_vector_type(8))) short bf16x8;
typedef __attribute__((ext_vector_type(4))) float f32x4;

// ws layout (floats):
#define WS_NORM 0
#define WS_ACTV (WS_NORM + NCOL)                      // 640
#define WS_FPART (WS_ACTV + BSZ * NCOL)               // 328320
#define WS_XB (WS_FPART + QSPLIT * KK * BSZ)          // 852608 (512*2048 ushort)
#define WS_THT (WS_XB + BSZ * DD / 2)                 // 1376896 (640*2048 ushort)
#define WS_PART (WS_THT + NCOL * DD / 2)              // 2032256 (16*512*640 ushort)

__device__ inline ushort f2b(float f) {               // f32 -> bf16 RNE
    unsigned u = __float_as_uint(f);
    u += 0x7FFF + ((u >> 16) & 1);
    return (ushort)(u >> 16);
}

// XOR-swizzled LDS index (ushort units).
#define SWZ(r, c) ((((r) * 128) + ((c) ^ (((r) & 7) << 3))))

// ---------------------------------------------------------------------------
// Kernel 1 (prep): [0,80) norm = colsum theta^2; [80,400) theta -> bf16
// transposed [640 n][2048 k]; [400,656) x -> bf16 [512][2048].
// ---------------------------------------------------------------------------
__global__ __launch_bounds__(256) void prep_kernel(const float* __restrict__ theta,
                                                   const float* __restrict__ x,
                                                   float* __restrict__ norm,
                                                   ushort* __restrict__ thT,
                                                   ushort* __restrict__ xb) {
    __shared__ float partial[32][8];
    __shared__ ushort sT[64][68];   // [n][k] tile; stride 68: write 8-way, read 2-way

    const int bid = blockIdx.x;
    const int t   = threadIdx.x;

    if (bid < 80) {                 // ---- norm ----
        const int c8  = bid * 8;
        const int col = c8 + (t & 7);
        const int g   = t >> 3;
        const float* p = theta + (size_t)g * NCOL + col;
        float s = 0.f;
#pragma unroll
        for (int j = 0; j < 64; ++j) {
            float v = p[(size_t)j * 32 * NCOL];
            s += v * v;
        }
        partial[g][t & 7] = s;
        __syncthreads();
        if (t < 8) {
            float acc = 0.f;
#pragma unroll
            for (int gg = 0; gg < 32; ++gg) acc += partial[gg][t];
            norm[c8 + t] = acc;
        }
    } else if (bid < 400) {         // ---- theta transpose+convert, 64x64 tiles ----
        const int tb    = bid - 80;        // 0..319 = 32 ktiles x 10 ntiles
        const int kz    = (tb & 31) * 64;
        const int nz    = (tb >> 5) * 64;
        const int c4    = t & 15;          // n-quad
        const int rbase = t >> 4;          // k-row base
#pragma unroll
        for (int i = 0; i < 4; ++i) {
            int r = rbase + i * 16;
            float4 v = *(const float4*)&theta[(size_t)(kz + r) * NCOL + nz + c4 * 4];
            sT[c4 * 4 + 0][r] = f2b(v.x);
            sT[c4 * 4 + 1][r] = f2b(v.y);
            sT[c4 * 4 + 2][r] = f2b(v.z);
            sT[c4 * 4 + 3][r] = f2b(v.w);
        }
        __syncthreads();
#pragma unroll
        for (int i = 0; i < 2; ++i) {
            int slot = t + i * 256;
            int rr   = slot >> 3;          // n row 0..63
            int cc   = (slot & 7) * 8;     // k col
            ushort4 w0 = *(const ushort4*)&sT[rr][cc];
            ushort4 w1 = *(const ushort4*)&sT[rr][cc + 4];
            ushort* dst = &thT[(size_t)(nz + rr) * DD + kz + cc];
            *(ushort4*)&dst[0] = w0;
            *(ushort4*)&dst[4] = w1;
        }
    } else {                        // ---- x convert ----
        const int b2 = bid - 400;          // 0..255
#pragma unroll
        for (int i = 0; i < 4; ++i) {
            int base = b2 * 4096 + i * 1024 + t * 4;
            float4 v = *(const float4*)&x[base];
            ushort4 w;
            w.x = f2b(v.x); w.y = f2b(v.y); w.z = f2b(v.z); w.w = f2b(v.w);
            *(ushort4*)&xb[base] = w;
        }
    }
}

// ---------------------------------------------------------------------------
// Kernel 2: split-K MFMA GEMM, ONE chunk per block (1280 blocks = 5/CU all
// resident; r7-verified +24us). XCD swizzle: m-tile = bid&7 -> per-XCD set
// 2.75MB < 4MB L2. part stored bf16 (halves round trip; absmax unchanged
// 0.125, r8-verified). Blocks [1280,1360): x -> out[:, :D] copy.
// ---------------------------------------------------------------------------
__global__ __launch_bounds__(256) void gemm_kernel(const ushort* __restrict__ xb,
                                                   const ushort* __restrict__ thT,
                                                   ushort* __restrict__ parth,
                                                   const float* __restrict__ x,
                                                   float* __restrict__ out) {
    __shared__ ushort lA[64 * 128];   // 16 KiB, swizzled
    __shared__ ushort lB[64 * 128];

    const int bx = blockIdx.x;
    if (bx >= 1280) {
        const int bid = bx - 1280;      // 0..79
        for (int i = bid * 256 + threadIdx.x; i < BSZ * (DD / 4); i += 80 * 256) {
            int r = i >> 9;
            int c = i & 511;
            float4 v = *(const float4*)&x[(size_t)r * DD + c * 4];
            *(float4*)&out[(size_t)r * OUTW + c * 4] = v;
        }
        return;
    }

    const int t    = threadIdx.x;
    const int lane = t & 63;
    const int wave = t >> 6;
    const int mt8  = bx & 7;           // m-tile -> XCD affinity
    const int rest = bx >> 3;          // 0..159
    const int bn   = (rest % 10) * 64;
    const int bm   = mt8 * 64;
    const int z    = rest / 10;        // 0..15
    const int kz   = z * GK;

    const ushort* gA = xb  + (size_t)bm * DD + kz;
    const ushort* gB = thT + (size_t)bn * DD + kz;

    const int srr = t >> 4;          // staging row base
    const int sss = t & 15;          // staging slot

    uint4 va[4], vb[4];
#pragma unroll
    for (int i = 0; i < 4; ++i) {
        int rr = srr + i * 16;
        va[i] = *(const uint4*)&gA[(size_t)rr * DD + sss * 8];
        vb[i] = *(const uint4*)&gB[(size_t)rr * DD + sss * 8];
    }
#pragma unroll
    for (int i = 0; i < 4; ++i) {
        int rr = srr + i * 16;
        *(uint4*)&lA[SWZ(rr, sss * 8)] = va[i];
        *(uint4*)&lB[SWZ(rr, sss * 8)] = vb[i];
    }
    __syncthreads();

    const int fr = lane & 15;
    const int g  = lane >> 4;
    const int mr = (wave >> 1) * 32 + fr;
    const int nr = (wave & 1) * 32 + fr;

    f32x4 acc[2][2] = {};
#pragma unroll
    for (int ks = 0; ks < 4; ++ks) {
        const int kc = ks * 32 + g * 8;
        bf16x8 a0 = *(const bf16x8*)&lA[SWZ(mr,      kc)];
        bf16x8 a1 = *(const bf16x8*)&lA[SWZ(mr + 16, kc)];
        bf16x8 b0 = *(const bf16x8*)&lB[SWZ(nr,      kc)];
        bf16x8 b1 = *(const bf16x8*)&lB[SWZ(nr + 16, kc)];
        acc[0][0] = __builtin_amdgcn_mfma_f32_16x16x32_bf16(a0, b0, acc[0][0], 0, 0, 0);
        acc[0][1] = __builtin_amdgcn_mfma_f32_16x16x32_bf16(a0, b1, acc[0][1], 0, 0, 0);
        acc[1][0] = __builtin_amdgcn_mfma_f32_16x16x32_bf16(a1, b0, acc[1][0], 0, 0, 0);
        acc[1][1] = __builtin_amdgcn_mfma_f32_16x16x32_bf16(a1, b1, acc[1][1], 0, 0, 0);
    }

    // C/D map: col=lane&15, row=(lane>>4)*4+reg [m89-verified]
    ushort* base = parth + (size_t)z * (BSZ * NCOL);
#pragma unroll
    for (int mt = 0; mt < 2; ++mt)
#pragma unroll
        for (int nt = 0; nt < 2; ++nt) {
            int row = bm + (wave >> 1) * 32 + mt * 16 + g * 4;
            int col = bn + (wave & 1) * 32 + nt * 16 + fr;
            ushort* dst = base + (size_t)row * NCOL + col;
#pragma unroll
            for (int reg = 0; reg < 4; ++reg)
                dst[(size_t)reg * NCOL] = f2b(acc[mt][nt][reg]);
        }
}

// ---------------------------------------------------------------------------
// Kernel 3: reduce 16 bf16 split-K partials (ushort2-vectorized), fold
// scale = exp(lws)/norm * log2e. 640 blocks.
// ---------------------------------------------------------------------------
__global__ __launch_bounds__(256) void reduce_kernel(const ushort* __restrict__ parth,
                                                     const float* __restrict__ norm,
                                                     const float* __restrict__ lws,
                                                     float* __restrict__ actv) {
    int i = (blockIdx.x * 256 + threadIdx.x) * 2;   // 0..655358 step 2
    float s0 = 0.f, s1 = 0.f;
#pragma unroll
    for (int q = 0; q < KSPLIT; ++q) {
        unsigned u = *(const unsigned*)&parth[(size_t)q * (BSZ * NCOL) + i];
        s0 += __uint_as_float(u << 16);
        s1 += __uint_as_float(u & 0xffff0000u);
    }
    const int col = i % NCOL;       // even; col+1 < 640
    const float sc0 = __builtin_amdgcn_exp2f(lws[col] * LOG2E) *
                      __builtin_amdgcn_rsqf(norm[col]) * LOG2E;
    const float sc1 = __builtin_amdgcn_exp2f(lws[col + 1] * LOG2E) *
                      __builtin_amdgcn_rsqf(norm[col + 1]) * LOG2E;
    float2 o = make_float2(s0 * sc0, s1 * sc1);
    *(float2*)&actv[i] = o;
}

// ---------------------------------------------------------------------------
// Kernel 4: pairwise L1 -> exp2 -> partial rowsum over 64-wide b2 chunk.
// v3: NO LDS, NO barrier. Comparison rows are block-uniform -> read via
// readfirstlane-uniform pointer so they live in SGPRs (s_load, K$-cached,
// scalar pipe). r5 showed not wave-starved; theory: LDS pipe (per-CU,
// 16 waves x 128 DS reads) was the serializer. Inner loop = pure VALU.
// NO device-scope atomics (write-through to HBM, +30us measured r2).
// ---------------------------------------------------------------------------
__global__ __launch_bounds__(256) void pairwise_kernel(const float* __restrict__ actv,
                                                       float* __restrict__ f_part) {
    const int k   = blockIdx.x;    // 0..127
    const int q   = blockIdx.y;    // 0..7
    const int tid = threadIdx.x;   // 0..255

    float a[2][PP];
#pragma unroll
    for (int r = 0; r < 2; ++r) {
        const float* ap = &actv[(size_t)(tid + r * 256) * NCOL + k * PP];
#pragma unroll
        for (int p = 0; p < PP; ++p) a[r][p] = ap[p];
    }

    // block-uniform base -> scalar loads
    const int ubase = __builtin_amdgcn_readfirstlane(q * 64 * NCOL + k * PP);
    const float* __restrict__ up = actv + ubase;

    float acc[2] = {0.f, 0.f};
#pragma unroll 8
    for (int j = 0; j < 64; ++j) {
        const float v0 = up[j * NCOL + 0];
        const float v1 = up[j * NCOL + 1];
        const float v2 = up[j * NCOL + 2];
        const float v3 = up[j * NCOL + 3];
        const float v4 = up[j * NCOL + 4];
#pragma unroll
        for (int r = 0; r < 2; ++r) {
            float s = fabsf(a[r][0] - v0) + fabsf(a[r][1] - v1) +
                      fabsf(a[r][2] - v2) + fabsf(a[r][3] - v3) +
                      fabsf(a[r][4] - v4);
            acc[r] += __builtin_amdgcn_exp2f(-s);   // actv pre-scaled by log2e
        }
    }

    float* fp = f_part + ((size_t)q * KK + k) * BSZ;
    fp[tid]       = acc[0];
    fp[tid + 256] = acc[1];
}

// ---------------------------------------------------------------------------
// Kernel 5: reduce f_part (L2-resident 2MB) into out[:, D:].
// ---------------------------------------------------------------------------
__global__ __launch_bounds__(256) void freduce_kernel(const float* __restrict__ f_part,
                                                      const float* __restrict__ bias,
                                                      float* __restrict__ out) {
    int i = blockIdx.x * 256 + threadIdx.x;   // 0..65535
    int k = i >> 9;
    int b = i & 511;
    float s = 0.f;
#pragma unroll
    for (int q = 0; q < QSPLIT; ++q)
        s += f_part[((size_t)q * KK + k) * BSZ + b];
    out[(size_t)b * OUTW + DD + k] = s - 1.0f + bias[k];
}

// ---------------------------------------------------------------------------
extern "C" void kernel_launch(void* const* d_in, const int* in_sizes, int n_in,
                              void* d_out, int out_size, void* d_ws, size_t ws_size,
                              hipStream_t stream) {
    const float* x     = (const float*)d_in[0];   // [512, 2048]
    const float* theta = (const float*)d_in[1];   // [2048, 128, 5]
    const float* lws   = (const float*)d_in[2];   // [128, 5]
    const float* bias  = (const float*)d_in[3];   // [128]
    float* out = (float*)d_out;                   // [512, 2176]

    float* ws     = (float*)d_ws;
    float* norm   = ws + WS_NORM;
    float* actv   = ws + WS_ACTV;
    float* f_part = ws + WS_FPART;
    ushort* xb    = (ushort*)(ws + WS_XB);
    ushort* thT   = (ushort*)(ws + WS_THT);
    ushort* parth = (ushort*)(ws + WS_PART);

    prep_kernel<<<656, 256, 0, stream>>>(theta, x, norm, thT, xb);
    gemm_kernel<<<1360, 256, 0, stream>>>(xb, thT, parth, x, out);
    reduce_kernel<<<640, 256, 0, stream>>>(parth, norm, lws, actv);
    pairwise_kernel<<<dim3(KK, QSPLIT), 256, 0, stream>>>(actv, f_part);
    freduce_kernel<<<256, 256, 0, stream>>>(f_part, bias, out);
}